// Round 1
// baseline (331.520 us; speedup 1.0000x reference)
//
#include <hip/hip_runtime.h>
#include <math.h>

// Sizes (fixed by the reference)
#define BATCH 16384
#define K_DIM 3072
#define NOUT  128      // E * (L2+1) = 8*16
#define NEXP  8

typedef float  f32x4  __attribute__((ext_vector_type(4)));
typedef __bf16 bf16x8 __attribute__((ext_vector_type(8)));
typedef unsigned int u32x4 __attribute__((ext_vector_type(4)));
typedef unsigned int u32x2 __attribute__((ext_vector_type(2)));

__device__ __forceinline__ unsigned short f2bf(float f) {
  union { float f; unsigned u; } v; v.f = f;
  unsigned u = v.u + 0x7fffu + ((v.u >> 16) & 1u);   // RNE
  return (unsigned short)(u >> 16);
}

// ---------------- kernel 1: w1 fp32 -> bf16 (128*3072 elements) ----------------
__global__ void cvt_w1_kernel(const float* __restrict__ w1, unsigned short* __restrict__ o) {
  int i = blockIdx.x * 256 + threadIdx.x;          // 98304 float4s
  f32x4 v = ((const f32x4*)w1)[i];
  u32x2 p = { (unsigned)f2bf(v.x) | ((unsigned)f2bf(v.y) << 16),
              (unsigned)f2bf(v.z) | ((unsigned)f2bf(v.w) << 16) };
  ((u32x2*)o)[i] = p;
}

// ---------------- kernel 2: router ----------------
// logits in fp64 (argmax tie safety), writes logp (B x 8), eidx (B),
// atomics: accs[0..7]=expert counts, accs[8]=sum lse^2
__global__ void router_kernel(const float* __restrict__ x, const float* __restrict__ rw,
                              const float* __restrict__ rb, float* __restrict__ logp,
                              int* __restrict__ eidx, float* __restrict__ accs) {
  __shared__ float rws[512];
  __shared__ float rbs[8];
  __shared__ int   hist[8];
  __shared__ float zred[4];
  const int tid = threadIdx.x;
  if (tid < 8) { hist[tid] = 0; rbs[tid] = rb[tid]; }
  for (int i = tid; i < 512; i += 256) rws[i] = rw[i];
  __syncthreads();

  const int b = blockIdx.x * 256 + tid;
  const float* xr = x + (size_t)b * K_DIM;
  double l[8];
#pragma unroll
  for (int e = 0; e < 8; ++e) l[e] = (double)rbs[e];
  for (int c = 0; c < 32; ++c) {
    double xv = (double)xr[c];
#pragma unroll
    for (int e = 0; e < 8; ++e) l[e] = fma(xv, (double)rws[e * 64 + c], l[e]);
  }
  for (int c = 0; c < 32; ++c) {
    double xv = (double)xr[1536 + c];
#pragma unroll
    for (int e = 0; e < 8; ++e) l[e] = fma(xv, (double)rws[e * 64 + 32 + c], l[e]);
  }
  double best = l[0]; int bi = 0;
#pragma unroll
  for (int e = 1; e < 8; ++e) if (l[e] > best) { best = l[e]; bi = e; }
  double s = 0.0;
#pragma unroll
  for (int e = 0; e < 8; ++e) s += exp(l[e] - best);
  double lse = best + log(s);
#pragma unroll
  for (int e = 0; e < 8; ++e) logp[(size_t)b * 8 + e] = (float)(l[e] - lse);
  eidx[b] = bi;
  atomicAdd(&hist[bi], 1);

  float z = (float)(lse * lse);
  for (int m = 1; m < 64; m <<= 1) z += __shfl_xor(z, m);
  if ((tid & 63) == 0) zred[tid >> 6] = z;
  __syncthreads();
  if (tid == 0) atomicAdd(&accs[8], zred[0] + zred[1] + zred[2] + zred[3]);
  if (tid < 8) atomicAdd(&accs[tid], (float)hist[tid]);
}

// ---------------- kernel 3: main GEMM + fused MoE epilogue ----------------
// BM=32 rows/block, all 128 outputs, BK=64. 512 blocks x 256 threads.
__global__ __launch_bounds__(256, 2) void moe_main_kernel(
    const float* __restrict__ x, const unsigned short* __restrict__ w1bf,
    const float* __restrict__ b1, const float* __restrict__ w2,
    const float* __restrict__ b2, const float* __restrict__ w3,
    const float* __restrict__ b3, const float* __restrict__ psqt,
    const float* __restrict__ st, const float* __restrict__ logp,
    const int* __restrict__ eidx, float* __restrict__ out,
    float* __restrict__ accs) {
  // tiles (K-loop) then reused as C (fp32 [32][132]) in epilogue
  __shared__ __align__(16) unsigned short stage[32 * 72 + 128 * 72];  // 23040 B
  __shared__ __align__(16) float w2s[8 * 964];                        // i-major, padded
  __shared__ float b1s[128], b2s[256], w3s[256], b3s[8], wred[4];

  const int tid = threadIdx.x;
  const int bm  = blockIdx.x;
  unsigned short* xs  = stage;
  unsigned short* wsd = stage + 32 * 72;
  float* Cl = (float*)stage;

  // stage epilogue constants (w2 transposed to [e][i*32+o], expert stride 964)
  for (int i = tid; i < 7680; i += 256) {
    int e = i / 960; int r = i - e * 960; int o = r / 30; int ii = r - o * 30;
    w2s[e * 964 + ii * 32 + o] = w2[i];
  }
  if (tid < 128) b1s[tid] = b1[tid];
  b2s[tid] = b2[tid];
  w3s[tid] = w3[tid];
  if (tid < 8) b3s[tid] = b3[tid];

  const int lane = tid & 63, wv = tid >> 6;
  const int l16 = lane & 15, lq = lane >> 4;
  const int rt = wv & 1;              // row-tile (16 rows)
  const int cb = (wv >> 1) * 4;       // first of 4 col-tiles

  // staging addresses
  const int xr0 = tid >> 4, xc4 = tid & 15;
  const float* gx0 = x + (size_t)(bm * 32 + xr0) * K_DIM + xc4 * 4;
  const float* gx1 = gx0 + (size_t)16 * K_DIM;
  const int xo0 = xr0 * 72 + xc4 * 4;
  const int xo1 = (xr0 + 16) * 72 + xc4 * 4;
  const int wr0 = tid >> 3, wc8 = tid & 7;
  const unsigned short* gw = w1bf + (size_t)wr0 * K_DIM + wc8 * 8;
  const int wo0 = wr0 * 72 + wc8 * 8;

  f32x4 acc[4];
#pragma unroll
  for (int c = 0; c < 4; ++c) acc[c] = (f32x4){0.f, 0.f, 0.f, 0.f};

  // prefetch kt=0
  f32x4 xv0 = *(const f32x4*)gx0;
  f32x4 xv1 = *(const f32x4*)gx1;
  u32x4 wv0 = *(const u32x4*)(gw);
  u32x4 wv1 = *(const u32x4*)(gw + 32 * K_DIM);
  u32x4 wv2 = *(const u32x4*)(gw + 64 * K_DIM);
  u32x4 wv3 = *(const u32x4*)(gw + 96 * K_DIM);

  const int abase = (rt * 16 + l16) * 72 + lq * 8;
  const int bbase = (cb * 16 + l16) * 72 + lq * 8;

  for (int kt = 0; kt < 48; ++kt) {
    __syncthreads();  // previous iter's LDS reads done
    {
      u32x2 p0 = { (unsigned)f2bf(xv0.x) | ((unsigned)f2bf(xv0.y) << 16),
                   (unsigned)f2bf(xv0.z) | ((unsigned)f2bf(xv0.w) << 16) };
      *(u32x2*)&xs[xo0] = p0;
      u32x2 p1 = { (unsigned)f2bf(xv1.x) | ((unsigned)f2bf(xv1.y) << 16),
                   (unsigned)f2bf(xv1.z) | ((unsigned)f2bf(xv1.w) << 16) };
      *(u32x2*)&xs[xo1] = p1;
      *(u32x4*)&wsd[wo0]           = wv0;
      *(u32x4*)&wsd[wo0 + 32 * 72] = wv1;
      *(u32x4*)&wsd[wo0 + 64 * 72] = wv2;
      *(u32x4*)&wsd[wo0 + 96 * 72] = wv3;
    }
    __syncthreads();  // tile visible
    if (kt < 47) {    // prefetch next tile into registers; overlaps MFMA below
      gx0 += 64; gx1 += 64;
      xv0 = *(const f32x4*)gx0;
      xv1 = *(const f32x4*)gx1;
      const unsigned short* g = gw + (kt + 1) * 64;
      wv0 = *(const u32x4*)(g);
      wv1 = *(const u32x4*)(g + 32 * K_DIM);
      wv2 = *(const u32x4*)(g + 64 * K_DIM);
      wv3 = *(const u32x4*)(g + 96 * K_DIM);
    }
#pragma unroll
    for (int ks = 0; ks < 2; ++ks) {
      bf16x8 af = *(const bf16x8*)&xs[abase + ks * 32];
#pragma unroll
      for (int c = 0; c < 4; ++c) {
        bf16x8 bfv = *(const bf16x8*)&wsd[bbase + c * 16 * 72 + ks * 32];
        acc[c] = __builtin_amdgcn_mfma_f32_16x16x32_bf16(af, bfv, acc[c], 0, 0, 0);
      }
    }
  }

  __syncthreads();  // all MFMA LDS reads done before overwriting tiles with C
#pragma unroll
  for (int c = 0; c < 4; ++c)
#pragma unroll
    for (int r = 0; r < 4; ++r)
      Cl[(rt * 16 + lq * 4 + r) * 132 + (cb + c) * 16 + l16] = acc[c][r];
  __syncthreads();

  // ---------------- epilogue: one thread per (sample, expert) ----------------
  const int bl = tid >> 3, e = tid & 7;
  const int bg = bm * 32 + bl;

  float a[16];
#pragma unroll
  for (int j = 0; j < 16; ++j) a[j] = Cl[bl * 132 + e * 16 + j] + b1s[e * 16 + j];

  float h[30];
#pragma unroll
  for (int j = 0; j < 15; ++j) {
    float v = a[j];
    h[j]      = fminf(fmaxf(v * v * (255.0f / 256.0f), 0.f), 1.f);
    h[15 + j] = fminf(fmaxf(v, 0.f), 1.f);
  }

  float acc2[32];
#pragma unroll
  for (int o = 0; o < 32; ++o) acc2[o] = b2s[e * 32 + o];
  const f32x4* wrow = (const f32x4*)&w2s[e * 964];
#pragma unroll
  for (int i = 0; i < 30; ++i) {
    float hv = h[i];
#pragma unroll
    for (int o4 = 0; o4 < 8; ++o4) {
      f32x4 wq = wrow[i * 8 + o4];
      acc2[o4 * 4 + 0] += hv * wq.x;
      acc2[o4 * 4 + 1] += hv * wq.y;
      acc2[o4 * 4 + 2] += hv * wq.z;
      acc2[o4 * 4 + 3] += hv * wq.w;
    }
  }

  float outv = b3s[e] + a[15];  // b3 + skip
#pragma unroll
  for (int o = 0; o < 32; ++o) {
    float l2v = fminf(fmaxf(acc2[o], 0.f), 1.f);
    outv += l2v * w3s[e * 32 + o];
  }

  // probe softmax over the 8 experts (lanes e=0..7 within each group of 8)
  float eo  = (outv + psqt[bg]) * 600.0f;
  float dd  = eo - st[bg];
  float err = dd * dd;
  float mn = err;
  mn = fminf(mn, __shfl_xor(mn, 1));
  mn = fminf(mn, __shfl_xor(mn, 2));
  mn = fminf(mn, __shfl_xor(mn, 4));
  float wexp = expf(-(err - mn));
  float ssum = wexp;
  ssum += __shfl_xor(ssum, 1); ssum += __shfl_xor(ssum, 2); ssum += __shfl_xor(ssum, 4);
  float pt  = wexp / ssum;
  float lpt = logf(fmaxf(pt, 1e-30f));
  float term = pt * (lpt - logp[(size_t)bg * 8 + e]);
  term += __shfl_xor(term, 1); term += __shfl_xor(term, 2); term += __shfl_xor(term, 4);
  float c1 = (e == 0) ? term : 0.f;
  c1 += __shfl_xor(c1, 8); c1 += __shfl_xor(c1, 16); c1 += __shfl_xor(c1, 32);
  if (lane == 0) wred[wv] = c1;

  if (e == eidx[bg]) out[bg] = outv;  // gating multiplier is exactly 1.0 in fwd

  __syncthreads();
  if (tid == 0) atomicAdd(&accs[9], wred[0] + wred[1] + wred[2] + wred[3]);
}

// ---------------- kernel 4: finalize scalar ----------------
__global__ void finalize_kernel(const float* __restrict__ accs, float* __restrict__ out) {
  if (threadIdx.x == 0) {
    float fsum = 0.f;
    for (int e = 0; e < 8; ++e) {
      float frac = accs[e] * (1.0f / 16384.0f);
      float f = fmaxf(0.05f - frac, 0.f);
      float c = fmaxf(frac - 0.5f, 0.f);
      fsum += f * f + c * c;
    }
    float aux   = fsum * 0.125f;             // floor_loss + cap_loss (each mean over E)
    float z     = accs[8] * (1.0f / 16384.0f);
    float probe = accs[9] * (1.0f / 16384.0f);
    out[BATCH] = 0.01f * aux + 0.001f * z + 0.01f * probe;
  }
}

extern "C" void kernel_launch(void* const* d_in, const int* in_sizes, int n_in,
                              void* d_out, int out_size, void* d_ws, size_t ws_size,
                              hipStream_t stream) {
  const float* x    = (const float*)d_in[0];
  // d_in[1] = ls_indices: unused (TEACHER_ALPHA == 0)
  const float* psqt = (const float*)d_in[2];
  const float* st   = (const float*)d_in[3];
  const float* rw   = (const float*)d_in[4];
  const float* rb   = (const float*)d_in[5];
  const float* w1   = (const float*)d_in[6];
  const float* b1   = (const float*)d_in[7];
  const float* w2   = (const float*)d_in[8];
  const float* b2   = (const float*)d_in[9];
  const float* w3   = (const float*)d_in[10];
  const float* b3   = (const float*)d_in[11];
  float* out = (float*)d_out;

  unsigned short* w1bf = (unsigned short*)d_ws;                       // 786432 B
  float* logp = (float*)((char*)d_ws + 786432);                      // 524288 B
  int*   eidx = (int*)((char*)d_ws + 786432 + 524288);               // 65536 B
  float* accs = (float*)((char*)d_ws + 786432 + 524288 + 65536);     // 16 floats

  hipMemsetAsync(accs, 0, 16 * sizeof(float), stream);
  cvt_w1_kernel<<<384, 256, 0, stream>>>(w1, w1bf);
  router_kernel<<<64, 256, 0, stream>>>(x, rw, rb, logp, eidx, accs);
  moe_main_kernel<<<512, 256, 0, stream>>>(x, w1bf, b1, w2, b2, w3, b3,
                                           psqt, st, logp, eidx, out, accs);
  finalize_kernel<<<1, 1, 0, stream>>>(accs, out);
}